// Round 3
// baseline (275.883 us; speedup 1.0000x reference)
//
#include <hip/hip_runtime.h>
#include <cmath>

#define NPTS 4096
#define NPOINT 204   // int(4096 * 0.05)
#define NPCT 5
#define MAXNS 409    // int(4096 * 0.10)
#define FPS_T 1024

typedef unsigned long long u64;

struct LossParams {
    int   nsample[NPCT];
    float r2[NPCT];
    float wscale[NPCT];   // (p*100)^2 / (B*NPOINT*NPCT)
    float expect_len;
};

// ---------------- DPP wave64 u64-max reduction (VALU-latency, no LDS) ------
// row_shr:n = 0x110|n, row_bcast15 = 0x142, row_bcast31 = 0x143.
// bound_ctrl=1 -> out-of-range lanes read 0, the identity for our keys
// (key = (d2bits<<32)|~idx > 0 always). shr1/2/4/8 -> row max in lane 16r+15;
// bcast15+bcast31 complete the full-wave max in lane 63.
template <int CTRL>
__device__ __forceinline__ u64 dpp_u64max(u64 v) {
    int lo = (int)(unsigned)v;
    int hi = (int)(unsigned)(v >> 32);
    unsigned slo = (unsigned)__builtin_amdgcn_update_dpp(0, lo, CTRL, 0xf, 0xf, true);
    unsigned shi = (unsigned)__builtin_amdgcn_update_dpp(0, hi, CTRL, 0xf, 0xf, true);
    u64 o = ((u64)shi << 32) | slo;
    return v > o ? v : o;
}

// ---------------------------------------------------------------------------
// Kernel 1: furthest point sampling, one block per batch, 1024 threads
// (16 waves = 4/SIMD for latency hiding). 203 serial argmax iterations;
// per-iter chain: 4-pt dist update -> u64-key DPP wave max (lane 63) ->
// LDS key write -> 1 barrier (ping-pong) -> lane-parallel 16-key merge
// (1 ds_read_b64 + 4 row-DPP steps + readlane) -> center fetch (b128).
// Tie semantics: first occurrence (smallest index) exactly, via ~idx in key.
// Distance: fp contract OFF, ((dx^2+dy^2)+dz^2) order (matches numpy ref).
// ---------------------------------------------------------------------------
__global__ __launch_bounds__(FPS_T) void fps_kernel(const float* __restrict__ pcd,
                                                    int* __restrict__ fps_idx) {
#pragma clang fp contract(off)
    __shared__ float4 pts[NPTS];        // 64 KB
    __shared__ u64 keys[2][16];         // ping-pong: 1 barrier/iter

    const int b = blockIdx.x;
    const int t = threadIdx.x;
    const int wave = t >> 6, lane = t & 63;
    const float* base = pcd + (size_t)b * NPTS * 3;

    float x[4], y[4], z[4], dist[4];
    #pragma unroll
    for (int k = 0; k < 4; ++k) {
        int n = k * FPS_T + t;
        float vx = base[3 * n + 0];
        float vy = base[3 * n + 1];
        float vz = base[3 * n + 2];
        pts[n] = make_float4(vx, vy, vz, 0.0f);
        x[k] = vx; y[k] = vy; z[k] = vz;
        dist[k] = 1e10f;
    }
    int* out = fps_idx + b * NPOINT;
    if (t == 0) out[0] = 0;
    __syncthreads();

    float4 c = pts[0];                  // broadcast LDS read
    for (int it = 1; it < NPOINT; ++it) {
        int bb = -1, bi = 0;
        #pragma unroll
        for (int k = 0; k < 4; ++k) {
            float dx = x[k] - c.x, dy = y[k] - c.y, dz = z[k] - c.z;
            float d  = (dx * dx + dy * dy) + dz * dz;
            float dk = fminf(dist[k], d);
            dist[k] = dk;
            int bits = __float_as_int(dk);   // nonneg: int cmp == float cmp
            if (bits > bb) { bb = bits; bi = k * FPS_T + t; }  // ascending idx: first-occurrence on tie
        }
        u64 key = ((u64)(unsigned)bb << 32) | (unsigned)~(unsigned)bi;
        key = dpp_u64max<0x111>(key);
        key = dpp_u64max<0x112>(key);
        key = dpp_u64max<0x114>(key);
        key = dpp_u64max<0x118>(key);
        key = dpp_u64max<0x142>(key);
        key = dpp_u64max<0x143>(key);
        if (lane == 63) keys[it & 1][wave] = key;
        __syncthreads();
        // lane-parallel merge of the 16 wave keys (rows hold identical copies)
        u64 kv = keys[it & 1][lane & 15];
        kv = dpp_u64max<0x111>(kv);
        kv = dpp_u64max<0x112>(kv);
        kv = dpp_u64max<0x114>(kv);
        kv = dpp_u64max<0x118>(kv);   // lane 16r+15 holds global max
        unsigned lo15 = (unsigned)__builtin_amdgcn_readlane((int)(unsigned)kv, 15);
        int last = (int)~lo15;
        c = pts[last];
        if (t == 0) out[it] = last;
    }
}

// ---------------------------------------------------------------------------
// Kernel 2: per (group, percentage) block.
// Phase A: 2-barrier ballot compaction — each wave owns a contiguous 1024-pt
// index segment; 16 sub-chunk ballot masks + local prefix stay in SGPRs;
// only wave totals cross waves. Index order preserved (pn2 truncation).
// Phase B: NN distance over REAL points only; pads (duplicates of gpts[0])
// contribute exactly 0.1 each analytically, and point 0's nn is 0 iff npad>0.
// 2-i register blocking for cntB>256 halves the broadcast LDS read issue.
// ---------------------------------------------------------------------------
__global__ __launch_bounds__(256) void group_kernel(const float* __restrict__ pcd,
                                                    const int* __restrict__ fps_idx,
                                                    float* __restrict__ out,
                                                    LossParams P) {
    const int pidx = blockIdx.y;
    const int g    = blockIdx.x;           // 0 .. B*NPOINT-1
    const int b    = g / NPOINT;
    const int m    = g - b * NPOINT;
    const int t    = threadIdx.x;
    const int wave = t >> 6, lane = t & 63;

    const int   ns = P.nsample[pidx];
    const float r2 = P.r2[pidx];

    __shared__ float4 gpts[MAXNS + 4];     // +4 sentinel pad for j-unroll
    __shared__ int    s_wtot[4];
    __shared__ float  s_part[4];

    const float* base = pcd + (size_t)b * NPTS * 3;
    int qi = fps_idx[b * NPOINT + m];      // uniform load
    float qx = base[3 * qi + 0], qy = base[3 * qi + 1], qz = base[3 * qi + 2];

    // ---- Phase A pass 1: ballot the wave's 16 sub-chunks of 64 points ----
    unsigned long long msk[16];
    int lbase[16];
    int run = 0;
    #pragma unroll 4
    for (int s = 0; s < 16; ++s) {
        int n = wave * 1024 + s * 64 + lane;
        float x = base[3 * n + 0];
        float y = base[3 * n + 1];
        float z = base[3 * n + 2];
        float d2;
        {
#pragma clang fp contract(off)
            float dx = qx - x, dy = qy - y, dz = qz - z;
            float aa = dx * dx, bb = dy * dy, cc = dz * dz;
            d2 = (aa + bb) + cc;
        }
        msk[s] = __ballot(d2 < r2);        // strict <, matches reference
        lbase[s] = run;
        run += __popcll(msk[s]);
    }
    if (lane == 0) s_wtot[wave] = run;
    __syncthreads();
    int w0 = s_wtot[0], w1 = s_wtot[1], w2 = s_wtot[2], w3 = s_wtot[3];
    int Bw = (wave > 0 ? w0 : 0) + (wave > 1 ? w1 : 0) + (wave > 2 ? w2 : 0);
    int cnt  = w0 + w1 + w2 + w3;
    int cntB = cnt < ns ? cnt : ns;        // real points kept
    const int npad = ns - cntB;

    // ---- Phase A pass 2: ordered compaction into LDS ----
    #pragma unroll 4
    for (int s = 0; s < 16; ++s) {
        int gb = Bw + lbase[s];            // wave-uniform
        if (gb >= ns) break;
        unsigned long long mk = msk[s];
        bool in = (mk >> lane) & 1ull;
        int pos = gb + __popcll(mk & ((1ull << lane) - 1ull));
        if (in && pos < ns) {
            int n = wave * 1024 + s * 64 + lane;
            gpts[pos] = make_float4(base[3 * n], base[3 * n + 1], base[3 * n + 2], 0.0f);
        }
    }
    if (t < 4) gpts[cntB + t] = make_float4(1e6f, 1e6f, 1e6f, 0.0f);  // sentinels
    __syncthreads();

    // ---- Phase B: nn among real points ----
    float sum = 0.0f;
    if (cntB > 256) {
        // 256 < cntB <= 409: every thread owns i0=t and (maybe) i1=t+256;
        // both share each j-column read -> LDS issue halved.
        const int i0 = t, i1 = t + 256;
        const bool a1 = i1 < cntB;
        float4 p0 = gpts[i0];
        float4 p1 = gpts[a1 ? i1 : 0];
        float n00 = 1e30f, n01 = 1e30f, n02 = 1e30f, n03 = 1e30f;
        float n10 = 1e30f, n11 = 1e30f, n12 = 1e30f, n13 = 1e30f;
        for (int jt = 0; jt < cntB; jt += 4) {
            float4 a = gpts[jt + 0];
            float4 bq = gpts[jt + 1];
            float4 cq = gpts[jt + 2];
            float4 dq = gpts[jt + 3];
            float dx, dy, dz, v;
            dx = p0.x - a.x;  dy = p0.y - a.y;  dz = p0.z - a.z;
            v = fmaf(dx, dx, fmaf(dy, dy, dz * dz));
            n00 = fminf(n00, (jt + 0 == i0) ? 1e30f : v);
            dx = p0.x - bq.x; dy = p0.y - bq.y; dz = p0.z - bq.z;
            v = fmaf(dx, dx, fmaf(dy, dy, dz * dz));
            n01 = fminf(n01, (jt + 1 == i0) ? 1e30f : v);
            dx = p0.x - cq.x; dy = p0.y - cq.y; dz = p0.z - cq.z;
            v = fmaf(dx, dx, fmaf(dy, dy, dz * dz));
            n02 = fminf(n02, (jt + 2 == i0) ? 1e30f : v);
            dx = p0.x - dq.x; dy = p0.y - dq.y; dz = p0.z - dq.z;
            v = fmaf(dx, dx, fmaf(dy, dy, dz * dz));
            n03 = fminf(n03, (jt + 3 == i0) ? 1e30f : v);

            dx = p1.x - a.x;  dy = p1.y - a.y;  dz = p1.z - a.z;
            v = fmaf(dx, dx, fmaf(dy, dy, dz * dz));
            n10 = fminf(n10, (jt + 0 == i1) ? 1e30f : v);
            dx = p1.x - bq.x; dy = p1.y - bq.y; dz = p1.z - bq.z;
            v = fmaf(dx, dx, fmaf(dy, dy, dz * dz));
            n11 = fminf(n11, (jt + 1 == i1) ? 1e30f : v);
            dx = p1.x - cq.x; dy = p1.y - cq.y; dz = p1.z - cq.z;
            v = fmaf(dx, dx, fmaf(dy, dy, dz * dz));
            n12 = fminf(n12, (jt + 2 == i1) ? 1e30f : v);
            dx = p1.x - dq.x; dy = p1.y - dq.y; dz = p1.z - dq.z;
            v = fmaf(dx, dx, fmaf(dy, dy, dz * dz));
            n13 = fminf(n13, (jt + 3 == i1) ? 1e30f : v);
        }
        float d0 = fminf(fminf(n00, n01), fminf(n02, n03));
        float d1 = fminf(fminf(n10, n11), fminf(n12, n13));
        // pads duplicate gpts[0] => point 0's nn is exactly 0 when npad>0
        if (!(i0 == 0 && npad > 0)) sum += sqrtf(d0);
        if (a1) sum += sqrtf(d1);
    } else {
        for (int i = t; i < cntB; i += 256) {
            float4 pi = gpts[i];
            float m0 = 1e30f, m1 = 1e30f, m2 = 1e30f, m3 = 1e30f;
            for (int jt = 0; jt < cntB; jt += 4) {
                float4 a = gpts[jt + 0];
                float4 bq = gpts[jt + 1];
                float4 cq = gpts[jt + 2];
                float4 dq = gpts[jt + 3];
                float dx, dy, dz, v;
                dx = pi.x - a.x;  dy = pi.y - a.y;  dz = pi.z - a.z;
                v = fmaf(dx, dx, fmaf(dy, dy, dz * dz));
                m0 = fminf(m0, (jt + 0 == i) ? 1e30f : v);
                dx = pi.x - bq.x; dy = pi.y - bq.y; dz = pi.z - bq.z;
                v = fmaf(dx, dx, fmaf(dy, dy, dz * dz));
                m1 = fminf(m1, (jt + 1 == i) ? 1e30f : v);
                dx = pi.x - cq.x; dy = pi.y - cq.y; dz = pi.z - cq.z;
                v = fmaf(dx, dx, fmaf(dy, dy, dz * dz));
                m2 = fminf(m2, (jt + 2 == i) ? 1e30f : v);
                dx = pi.x - dq.x; dy = pi.y - dq.y; dz = pi.z - dq.z;
                v = fmaf(dx, dx, fmaf(dy, dy, dz * dz));
                m3 = fminf(m3, (jt + 3 == i) ? 1e30f : v);
            }
            float dmin = fminf(fminf(m0, m1), fminf(m2, m3));
            if (!(i == 0 && npad > 0)) sum += sqrtf(dmin);
        }
    }
    #pragma unroll
    for (int off = 32; off; off >>= 1) sum += __shfl_down(sum, off);
    if (lane == 0) s_part[wave] = sum;
    __syncthreads();
    if (t == 0) {
        // every entry contributes |nn + 0.1| = nn + 0.1; pads/excluded have nn=0
        float tot = s_part[0] + s_part[1] + s_part[2] + s_part[3] + 0.1f * (float)ns;
        float u  = tot / (float)ns;
        float du = u - P.expect_len;
        float contrib = du * du / (P.expect_len + 0.1f) * P.wscale[pidx];
        atomicAdd(out, contrib);
    }
}

extern "C" void kernel_launch(void* const* d_in, const int* in_sizes, int n_in,
                              void* d_out, int out_size, void* d_ws, size_t ws_size,
                              hipStream_t stream) {
    const float* pcd = (const float*)d_in[0];
    const int B = in_sizes[0] / (NPTS * 3);   // = 2
    float* out = (float*)d_out;
    int* fps = (int*)d_ws;                    // B*NPOINT ints

    hipMemsetAsync(d_out, 0, out_size * sizeof(float), stream);

    fps_kernel<<<dim3(B), dim3(FPS_T), 0, stream>>>(pcd, fps);

    LossParams P;
    const double ps[NPCT] = {0.02, 0.04, 0.06, 0.08, 0.10};
    for (int i = 0; i < NPCT; ++i) {
        P.nsample[i] = (int)(NPTS * ps[i]);
        double r = std::sqrt(ps[i] * 1.0);
        P.r2[i] = (float)(r * r);
        double w = (ps[i] * 100.0) * (ps[i] * 100.0);
        P.wscale[i] = (float)(w / (double)(B * NPOINT * NPCT));
    }
    P.expect_len = (float)std::sqrt(3.14159265358979323846 / (double)NPTS);

    dim3 grid(B * NPOINT, NPCT);
    group_kernel<<<grid, dim3(256), 0, stream>>>(pcd, fps, out, P);
}

// Round 4
// 236.840 us; speedup vs baseline: 1.1649x; 1.1649x over previous
//
#include <hip/hip_runtime.h>
#include <cmath>

#define NPTS 4096
#define NPOINT 204   // int(4096 * 0.05)
#define NPCT 5
#define MAXNS 409    // int(4096 * 0.10)
#define FPS_T 512
#define NGROUP 408   // B * NPOINT
#define NPART (NGROUP * NPCT)

typedef unsigned long long u64;

struct LossParams {
    int   nsample[NPCT];
    float r2[NPCT];
    float wscale[NPCT];   // (p*100)^2 / (B*NPOINT*NPCT)
    float expect_len;
};

// ---------------- DPP wave64 reductions ------------------------------------
// row_shr:n = 0x110|n, row_bcast15 = 0x142, row_bcast31 = 0x143.
// imax: bound_ctrl=1 (0-fill) — identity for nonneg float-bits.
// imin: bound_ctrl=0, old=INT_MAX — identity for min.
// These fuse into single v_max_i32/v_min_i32 with DPP on src0.
template <int CTRL>
__device__ __forceinline__ int dpp_imax(int v) {
    int t = __builtin_amdgcn_update_dpp(0, v, CTRL, 0xf, 0xf, true);
    return v > t ? v : t;
}
template <int CTRL>
__device__ __forceinline__ int dpp_imin(int v) {
    int t = __builtin_amdgcn_update_dpp(0x7fffffff, v, CTRL, 0xf, 0xf, false);
    return v < t ? v : t;
}
__device__ __forceinline__ int wave_max_i(int v) {
    v = dpp_imax<0x111>(v); v = dpp_imax<0x112>(v);
    v = dpp_imax<0x114>(v); v = dpp_imax<0x118>(v);
    v = dpp_imax<0x142>(v); v = dpp_imax<0x143>(v);
    return __builtin_amdgcn_readlane(v, 63);
}
__device__ __forceinline__ int wave_min_i(int v) {
    v = dpp_imin<0x111>(v); v = dpp_imin<0x112>(v);
    v = dpp_imin<0x114>(v); v = dpp_imin<0x118>(v);
    v = dpp_imin<0x142>(v); v = dpp_imin<0x143>(v);
    return __builtin_amdgcn_readlane(v, 63);
}
// u64 max (5 instrs/step) — used ONLY for the 3-step cross-wave merge.
template <int CTRL>
__device__ __forceinline__ u64 dpp_u64max(u64 v) {
    int lo = (int)(unsigned)v;
    int hi = (int)(unsigned)(v >> 32);
    unsigned slo = (unsigned)__builtin_amdgcn_update_dpp(0, lo, CTRL, 0xf, 0xf, true);
    unsigned shi = (unsigned)__builtin_amdgcn_update_dpp(0, hi, CTRL, 0xf, 0xf, true);
    u64 o = ((u64)shi << 32) | slo;
    return v > o ? v : o;
}

// ---------------------------------------------------------------------------
// Kernel 1: FPS, one block per batch, 512 threads (8 waves = 2/SIMD).
// Per iter: 8-pt dist update -> int-bits DPP wave max (1 instr/step) ->
// tie-index DPP wave min -> lane0 writes u64 key -> 1 barrier (ping-pong) ->
// lane-parallel 8-key merge (3 u64-DPP steps + readlane) -> b128 center fetch.
// Tie semantics: first occurrence (smallest global index) exactly.
// Distance: fp contract OFF, ((dx^2+dy^2)+dz^2) order (matches numpy ref).
// ---------------------------------------------------------------------------
__global__ __launch_bounds__(FPS_T) void fps_kernel(const float* __restrict__ pcd,
                                                    int* __restrict__ fps_idx) {
#pragma clang fp contract(off)
    __shared__ float4 pts[NPTS];        // 64 KB
    __shared__ u64 keys[2][8];          // ping-pong: 1 barrier/iter

    const int b = blockIdx.x;
    const int t = threadIdx.x;
    const int wave = t >> 6, lane = t & 63;
    const float* base = pcd + (size_t)b * NPTS * 3;

    float x[8], y[8], z[8], dist[8];
    #pragma unroll
    for (int k = 0; k < 8; ++k) {
        int n = k * FPS_T + t;
        float vx = base[3 * n + 0];
        float vy = base[3 * n + 1];
        float vz = base[3 * n + 2];
        pts[n] = make_float4(vx, vy, vz, 0.0f);
        x[k] = vx; y[k] = vy; z[k] = vz;
        dist[k] = 1e10f;
    }
    int* out = fps_idx + b * NPOINT;
    if (t == 0) out[0] = 0;
    __syncthreads();

    float4 c = pts[0];
    for (int it = 1; it < NPOINT; ++it) {
        int bb = -1, bi = 0;
        #pragma unroll
        for (int k = 0; k < 8; ++k) {
            float dx = x[k] - c.x, dy = y[k] - c.y, dz = z[k] - c.z;
            float d  = (dx * dx + dy * dy) + dz * dz;
            float dk = fminf(dist[k], d);
            dist[k] = dk;
            int bits = __float_as_int(dk);   // nonneg: int cmp == float cmp
            if (bits > bb) { bb = bits; bi = k * FPS_T + t; }  // ascending idx: first-occ on tie
        }
        int wmax = wave_max_i(bb);
        int cand = (bb == wmax) ? bi : 0x7fffffff;
        int widx = wave_min_i(cand);         // smallest index among ties
        if (lane == 0)
            keys[it & 1][wave] =
                ((u64)(unsigned)wmax << 32) | (unsigned)~(unsigned)widx;
        __syncthreads();
        u64 kv = keys[it & 1][lane & 7];     // rows hold identical copies
        kv = dpp_u64max<0x111>(kv);
        kv = dpp_u64max<0x112>(kv);
        kv = dpp_u64max<0x114>(kv);          // lane 16r+7 holds global max
        unsigned lo7 = (unsigned)__builtin_amdgcn_readlane((int)(unsigned)kv, 7);
        int last = (int)~lo7;
        c = pts[last];
        if (t == 0) out[it] = last;
    }
}

// ---------------------------------------------------------------------------
// Kernel 2: per (group, percentage) block.
// Phase A: 2-barrier ballot compaction (wave-segmented, order-preserving),
// storing (x,y,z,|p|^2) per kept point.
// Phase B: nn among real points via h_j = sq_j - 2*dot(p_i,p_j);
// dmin_i = sq_i + min_j h_j (Gram form, same as reference). Pads handled
// analytically (contribute 0.1 each; point 0's nn = 0 iff npad>0).
// Per-block partial goes to a PRIVATE slot (no global atomic contention).
// ---------------------------------------------------------------------------
__global__ __launch_bounds__(256) void group_kernel(const float* __restrict__ pcd,
                                                    const int* __restrict__ fps_idx,
                                                    float* __restrict__ partials,
                                                    LossParams P) {
    const int pidx = blockIdx.y;
    const int g    = blockIdx.x;           // 0 .. NGROUP-1
    const int b    = g / NPOINT;
    const int m    = g - b * NPOINT;
    const int t    = threadIdx.x;
    const int wave = t >> 6, lane = t & 63;

    const int   ns = P.nsample[pidx];
    const float r2 = P.r2[pidx];

    __shared__ float4 gpts[MAXNS + 4];     // +4 sentinel pad for j-unroll
    __shared__ int    s_wtot[4];
    __shared__ float  s_part[4];

    const float* base = pcd + (size_t)b * NPTS * 3;
    int qi = fps_idx[b * NPOINT + m];
    float qx = base[3 * qi + 0], qy = base[3 * qi + 1], qz = base[3 * qi + 2];

    // ---- Phase A pass 1: ballot the wave's 16 sub-chunks of 64 points ----
    unsigned long long msk[16];
    int lbase[16];
    int run = 0;
    #pragma unroll 4
    for (int s = 0; s < 16; ++s) {
        int n = wave * 1024 + s * 64 + lane;
        float x = base[3 * n + 0];
        float y = base[3 * n + 1];
        float z = base[3 * n + 2];
        float d2;
        {
#pragma clang fp contract(off)
            float dx = qx - x, dy = qy - y, dz = qz - z;
            float aa = dx * dx, bb = dy * dy, cc = dz * dz;
            d2 = (aa + bb) + cc;
        }
        msk[s] = __ballot(d2 < r2);        // strict <, matches reference
        lbase[s] = run;
        run += __popcll(msk[s]);
    }
    if (lane == 0) s_wtot[wave] = run;
    __syncthreads();
    int w0 = s_wtot[0], w1 = s_wtot[1], w2 = s_wtot[2], w3 = s_wtot[3];
    int Bw = (wave > 0 ? w0 : 0) + (wave > 1 ? w1 : 0) + (wave > 2 ? w2 : 0);
    int cnt  = w0 + w1 + w2 + w3;
    int cntB = cnt < ns ? cnt : ns;        // real points kept
    const int npad = ns - cntB;

    // ---- Phase A pass 2: ordered compaction into LDS, w = |p|^2 ----
    #pragma unroll 4
    for (int s = 0; s < 16; ++s) {
        int gb = Bw + lbase[s];            // wave-uniform
        if (gb >= ns) break;
        unsigned long long mk = msk[s];
        bool in = (mk >> lane) & 1ull;
        int pos = gb + __popcll(mk & ((1ull << lane) - 1ull));
        if (in && pos < ns) {
            int n = wave * 1024 + s * 64 + lane;
            float x = base[3 * n], y = base[3 * n + 1], z = base[3 * n + 2];
            float sq = fmaf(x, x, fmaf(y, y, z * z));
            gpts[pos] = make_float4(x, y, z, sq);
        }
    }
    if (t < 4) gpts[cntB + t] = make_float4(1e6f, 1e6f, 1e6f, 3e12f);  // sentinels (huge h)
    __syncthreads();

    // ---- Phase B: nn among real points (Gram form) ----
    float sum = 0.0f;
    if (cntB > 256) {
        // 256 < cntB <= 409: thread owns i0=t and (maybe) i1=t+256; shared j reads.
        const int i0 = t, i1 = t + 256;
        const bool a1 = i1 < cntB;
        float4 p0 = gpts[i0];
        float4 p1 = gpts[a1 ? i1 : 0];
        float h00 = 1e30f, h01 = 1e30f, h02 = 1e30f, h03 = 1e30f;
        float h10 = 1e30f, h11 = 1e30f, h12 = 1e30f, h13 = 1e30f;
        for (int jt = 0; jt < cntB; jt += 4) {
            float4 a = gpts[jt + 0];
            float4 bq = gpts[jt + 1];
            float4 cq = gpts[jt + 2];
            float4 dq = gpts[jt + 3];
            float tt, h;
            tt = p0.x * a.x;  tt = fmaf(p0.y, a.y, tt);  tt = fmaf(p0.z, a.z, tt);
            h = fmaf(-2.0f, tt, a.w);
            h00 = fminf(h00, (jt + 0 == i0) ? 1e30f : h);
            tt = p0.x * bq.x; tt = fmaf(p0.y, bq.y, tt); tt = fmaf(p0.z, bq.z, tt);
            h = fmaf(-2.0f, tt, bq.w);
            h01 = fminf(h01, (jt + 1 == i0) ? 1e30f : h);
            tt = p0.x * cq.x; tt = fmaf(p0.y, cq.y, tt); tt = fmaf(p0.z, cq.z, tt);
            h = fmaf(-2.0f, tt, cq.w);
            h02 = fminf(h02, (jt + 2 == i0) ? 1e30f : h);
            tt = p0.x * dq.x; tt = fmaf(p0.y, dq.y, tt); tt = fmaf(p0.z, dq.z, tt);
            h = fmaf(-2.0f, tt, dq.w);
            h03 = fminf(h03, (jt + 3 == i0) ? 1e30f : h);

            tt = p1.x * a.x;  tt = fmaf(p1.y, a.y, tt);  tt = fmaf(p1.z, a.z, tt);
            h = fmaf(-2.0f, tt, a.w);
            h10 = fminf(h10, (jt + 0 == i1) ? 1e30f : h);
            tt = p1.x * bq.x; tt = fmaf(p1.y, bq.y, tt); tt = fmaf(p1.z, bq.z, tt);
            h = fmaf(-2.0f, tt, bq.w);
            h11 = fminf(h11, (jt + 1 == i1) ? 1e30f : h);
            tt = p1.x * cq.x; tt = fmaf(p1.y, cq.y, tt); tt = fmaf(p1.z, cq.z, tt);
            h = fmaf(-2.0f, tt, cq.w);
            h12 = fminf(h12, (jt + 2 == i1) ? 1e30f : h);
            tt = p1.x * dq.x; tt = fmaf(p1.y, dq.y, tt); tt = fmaf(p1.z, dq.z, tt);
            h = fmaf(-2.0f, tt, dq.w);
            h13 = fminf(h13, (jt + 3 == i1) ? 1e30f : h);
        }
        float d0 = fmaxf(p0.w + fminf(fminf(h00, h01), fminf(h02, h03)), 0.0f);
        float d1 = fmaxf(p1.w + fminf(fminf(h10, h11), fminf(h12, h13)), 0.0f);
        if (!(i0 == 0 && npad > 0)) sum += sqrtf(d0);
        if (a1) sum += sqrtf(d1);
    } else {
        for (int i = t; i < cntB; i += 256) {
            float4 pi = gpts[i];
            float m0 = 1e30f, m1 = 1e30f, m2 = 1e30f, m3 = 1e30f;
            for (int jt = 0; jt < cntB; jt += 4) {
                float4 a = gpts[jt + 0];
                float4 bq = gpts[jt + 1];
                float4 cq = gpts[jt + 2];
                float4 dq = gpts[jt + 3];
                float tt, h;
                tt = pi.x * a.x;  tt = fmaf(pi.y, a.y, tt);  tt = fmaf(pi.z, a.z, tt);
                h = fmaf(-2.0f, tt, a.w);
                m0 = fminf(m0, (jt + 0 == i) ? 1e30f : h);
                tt = pi.x * bq.x; tt = fmaf(pi.y, bq.y, tt); tt = fmaf(pi.z, bq.z, tt);
                h = fmaf(-2.0f, tt, bq.w);
                m1 = fminf(m1, (jt + 1 == i) ? 1e30f : h);
                tt = pi.x * cq.x; tt = fmaf(pi.y, cq.y, tt); tt = fmaf(pi.z, cq.z, tt);
                h = fmaf(-2.0f, tt, cq.w);
                m2 = fminf(m2, (jt + 2 == i) ? 1e30f : h);
                tt = pi.x * dq.x; tt = fmaf(pi.y, dq.y, tt); tt = fmaf(pi.z, dq.z, tt);
                h = fmaf(-2.0f, tt, dq.w);
                m3 = fminf(m3, (jt + 3 == i) ? 1e30f : h);
            }
            float dmin = fmaxf(pi.w + fminf(fminf(m0, m1), fminf(m2, m3)), 0.0f);
            if (!(i == 0 && npad > 0)) sum += sqrtf(dmin);
        }
    }
    #pragma unroll
    for (int off = 32; off; off >>= 1) sum += __shfl_down(sum, off);
    if (lane == 0) s_part[wave] = sum;
    __syncthreads();
    if (t == 0) {
        float tot = s_part[0] + s_part[1] + s_part[2] + s_part[3] + 0.1f * (float)ns;
        float u  = tot / (float)ns;
        float du = u - P.expect_len;
        partials[pidx * NGROUP + g] = du * du / (P.expect_len + 0.1f) * P.wscale[pidx];
    }
}

// ---------------------------------------------------------------------------
// Kernel 3: sum the 2040 per-block partials -> d_out (no atomics anywhere).
// ---------------------------------------------------------------------------
__global__ __launch_bounds__(256) void reduce_kernel(const float* __restrict__ partials,
                                                     float* __restrict__ out) {
    const int t = threadIdx.x;
    __shared__ float sp[4];
    float s = 0.0f;
    for (int i = t; i < NPART; i += 256) s += partials[i];
    #pragma unroll
    for (int off = 32; off; off >>= 1) s += __shfl_down(s, off);
    if ((t & 63) == 0) sp[t >> 6] = s;
    __syncthreads();
    if (t == 0) out[0] = sp[0] + sp[1] + sp[2] + sp[3];
}

extern "C" void kernel_launch(void* const* d_in, const int* in_sizes, int n_in,
                              void* d_out, int out_size, void* d_ws, size_t ws_size,
                              hipStream_t stream) {
    const float* pcd = (const float*)d_in[0];
    const int B = in_sizes[0] / (NPTS * 3);   // = 2
    float* out = (float*)d_out;
    int*   fps = (int*)d_ws;                  // [0, NGROUP) ints
    float* partials = (float*)d_ws + NGROUP;  // [NGROUP, NGROUP+NPART) floats

    fps_kernel<<<dim3(B), dim3(FPS_T), 0, stream>>>(pcd, fps);

    LossParams P;
    const double ps[NPCT] = {0.02, 0.04, 0.06, 0.08, 0.10};
    for (int i = 0; i < NPCT; ++i) {
        P.nsample[i] = (int)(NPTS * ps[i]);
        double r = std::sqrt(ps[i] * 1.0);
        P.r2[i] = (float)(r * r);
        double w = (ps[i] * 100.0) * (ps[i] * 100.0);
        P.wscale[i] = (float)(w / (double)(B * NPOINT * NPCT));
    }
    P.expect_len = (float)std::sqrt(3.14159265358979323846 / (double)NPTS);

    dim3 grid(NGROUP, NPCT);
    group_kernel<<<grid, dim3(256), 0, stream>>>(pcd, fps, partials, P);
    reduce_kernel<<<dim3(1), dim3(256), 0, stream>>>(partials, out);
}

// Round 5
// 215.723 us; speedup vs baseline: 1.2789x; 1.0979x over previous
//
#include <hip/hip_runtime.h>
#include <cmath>

#define NPTS 4096
#define NPOINT 204   // int(4096 * 0.05)
#define NPCT 5
#define MAXNS 409    // int(4096 * 0.10)
#define FPS_T 256
#define NGROUP 408   // B * NPOINT
#define NPART (NGROUP * NPCT)

typedef unsigned long long u64;
typedef float f32x2 __attribute__((ext_vector_type(2)));

struct LossParams {
    int   nsample[NPCT];
    float r2[NPCT];
    float wscale[NPCT];   // (p*100)^2 / (B*NPOINT*NPCT)
    float expect_len;
};

// ---------------- DPP wave64 reductions ------------------------------------
// row_shr:n = 0x110|n, row_bcast15 = 0x142, row_bcast31 = 0x143.
// imax: bound_ctrl=1 (0-fill) — identity for nonneg float-bits.
// imin: bound_ctrl=0, old=INT_MAX — identity for min.
// These fuse into single v_max_i32/v_min_i32 with DPP on src0.
template <int CTRL>
__device__ __forceinline__ int dpp_imax(int v) {
    int t = __builtin_amdgcn_update_dpp(0, v, CTRL, 0xf, 0xf, true);
    return v > t ? v : t;
}
template <int CTRL>
__device__ __forceinline__ int dpp_imin(int v) {
    int t = __builtin_amdgcn_update_dpp(0x7fffffff, v, CTRL, 0xf, 0xf, false);
    return v < t ? v : t;
}
__device__ __forceinline__ int wave_max_i(int v) {
    v = dpp_imax<0x111>(v); v = dpp_imax<0x112>(v);
    v = dpp_imax<0x114>(v); v = dpp_imax<0x118>(v);
    v = dpp_imax<0x142>(v); v = dpp_imax<0x143>(v);
    return __builtin_amdgcn_readlane(v, 63);
}
__device__ __forceinline__ int wave_min_i(int v) {
    v = dpp_imin<0x111>(v); v = dpp_imin<0x112>(v);
    v = dpp_imin<0x114>(v); v = dpp_imin<0x118>(v);
    v = dpp_imin<0x142>(v); v = dpp_imin<0x143>(v);
    return __builtin_amdgcn_readlane(v, 63);
}
// u64 max (5 instrs/step) — used ONLY for the 2-step cross-wave merge.
template <int CTRL>
__device__ __forceinline__ u64 dpp_u64max(u64 v) {
    int lo = (int)(unsigned)v;
    int hi = (int)(unsigned)(v >> 32);
    unsigned slo = (unsigned)__builtin_amdgcn_update_dpp(0, lo, CTRL, 0xf, 0xf, true);
    unsigned shi = (unsigned)__builtin_amdgcn_update_dpp(0, hi, CTRL, 0xf, 0xf, true);
    u64 o = ((u64)shi << 32) | slo;
    return v > o ? v : o;
}

// ---------------------------------------------------------------------------
// Kernel 1: FPS, one block per batch, 256 threads (4 waves, 1/SIMD — R2's
// shape, which beat 512/1024). Per iter: packed-f32 dist update (float2
// vector ops -> v_pk_add/v_pk_mul candidates, bit-identical rounding) ->
// int-bits DPP wave max -> tie-index DPP wave min -> lane0 writes u64 key ->
// ONE barrier (ping-pong) -> lane-parallel 4-key merge (2 u64-DPP steps +
// readlane) -> b128 center fetch. Tie: first occurrence (smallest index).
// Distance: fp contract OFF, ((dx^2+dy^2)+dz^2) order (matches numpy ref).
// ---------------------------------------------------------------------------
__global__ __launch_bounds__(FPS_T) void fps_kernel(const float* __restrict__ pcd,
                                                    int* __restrict__ fps_idx) {
#pragma clang fp contract(off)
    __shared__ float4 pts[NPTS];        // 64 KB
    __shared__ u64 keys[2][4];          // ping-pong: 1 barrier/iter

    const int b = blockIdx.x;
    const int t = threadIdx.x;
    const int wave = t >> 6, lane = t & 63;
    const float* base = pcd + (size_t)b * NPTS * 3;

    f32x2 X[8], Y[8], Z[8], D[8];
    #pragma unroll
    for (int q = 0; q < 8; ++q) {
        int n0 = (2 * q) * FPS_T + t;
        int n1 = (2 * q + 1) * FPS_T + t;
        float x0 = base[3 * n0 + 0], y0 = base[3 * n0 + 1], z0 = base[3 * n0 + 2];
        float x1 = base[3 * n1 + 0], y1 = base[3 * n1 + 1], z1 = base[3 * n1 + 2];
        pts[n0] = make_float4(x0, y0, z0, 0.0f);
        pts[n1] = make_float4(x1, y1, z1, 0.0f);
        X[q] = (f32x2){x0, x1};
        Y[q] = (f32x2){y0, y1};
        Z[q] = (f32x2){z0, z1};
        D[q] = (f32x2){1e10f, 1e10f};
    }
    int* out = fps_idx + b * NPOINT;
    if (t == 0) out[0] = 0;
    __syncthreads();

    float4 c = pts[0];
    for (int it = 1; it < NPOINT; ++it) {
        f32x2 cxx = (f32x2){c.x, c.x};
        f32x2 cyy = (f32x2){c.y, c.y};
        f32x2 czz = (f32x2){c.z, c.z};
        int bb = -1, bi = 0;
        #pragma unroll
        for (int q = 0; q < 8; ++q) {
            f32x2 dx = X[q] - cxx, dy = Y[q] - cyy, dz = Z[q] - czz;
            f32x2 d  = (dx * dx + dy * dy) + dz * dz;   // pk_mul/pk_add, scalar-identical
            f32x2 dd = D[q];
            float d0 = fminf(dd.x, d.x);
            float d1 = fminf(dd.y, d.y);
            D[q] = (f32x2){d0, d1};
            int b0 = __float_as_int(d0);                 // nonneg: int cmp == float cmp
            int b1 = __float_as_int(d1);
            if (b0 > bb) { bb = b0; bi = (2 * q) * FPS_T + t; }
            if (b1 > bb) { bb = b1; bi = (2 * q + 1) * FPS_T + t; }
        }
        int wmax = wave_max_i(bb);
        int cand = (bb == wmax) ? bi : 0x7fffffff;
        int widx = wave_min_i(cand);         // smallest index among ties
        if (lane == 0)
            keys[it & 1][wave] =
                ((u64)(unsigned)wmax << 32) | (unsigned)~(unsigned)widx;
        __syncthreads();
        u64 kv = keys[it & 1][lane & 3];     // 16-rows hold identical copies
        kv = dpp_u64max<0x111>(kv);
        kv = dpp_u64max<0x112>(kv);          // lane 16r+3 holds global max
        unsigned lo3 = (unsigned)__builtin_amdgcn_readlane((int)(unsigned)kv, 3);
        int last = (int)~lo3;
        c = pts[last];
        if (t == 0) out[it] = last;
    }
}

// ---------------------------------------------------------------------------
// Kernel 2: one block per (group, percentage), 1-D grid with pidx = blk % 5
// so heavy (p=0.10) and light blocks interleave in dispatch order.
// Phase A: 2-barrier ballot compaction (wave-segmented, order-preserving),
// storing (x,y,z,|p|^2).
// Phase B: 2nd-smallest-including-self via v_med3_f32 min2 tracking — exact
// reference semantics (KNN k=2 incl. self-distance 0), no diagonal branch.
// Pads analytic: contribute 0.1 each; point 0's nn = 0 iff npad>0.
// ---------------------------------------------------------------------------
__global__ __launch_bounds__(256) void group_kernel(const float* __restrict__ pcd,
                                                    const int* __restrict__ fps_idx,
                                                    float* __restrict__ partials,
                                                    LossParams P) {
    const int xid  = blockIdx.x;           // 0 .. NPART-1
    const int pidx = xid % NPCT;
    const int g    = xid / NPCT;           // 0 .. NGROUP-1
    const int b    = g / NPOINT;
    const int m    = g - b * NPOINT;
    const int t    = threadIdx.x;
    const int wave = t >> 6, lane = t & 63;

    const int   ns = P.nsample[pidx];
    const float r2 = P.r2[pidx];

    __shared__ float4 gpts[MAXNS + 8];     // +8 sentinel pad for j-unroll
    __shared__ int    s_wtot[4];
    __shared__ float  s_part[4];

    const float* base = pcd + (size_t)b * NPTS * 3;
    int qi = fps_idx[b * NPOINT + m];
    float qx = base[3 * qi + 0], qy = base[3 * qi + 1], qz = base[3 * qi + 2];

    // ---- Phase A pass 1: ballot the wave's 16 sub-chunks of 64 points ----
    unsigned long long msk[16];
    int lbase[16];
    int run = 0;
    #pragma unroll 4
    for (int s = 0; s < 16; ++s) {
        int n = wave * 1024 + s * 64 + lane;
        float x = base[3 * n + 0];
        float y = base[3 * n + 1];
        float z = base[3 * n + 2];
        float d2;
        {
#pragma clang fp contract(off)
            float dx = qx - x, dy = qy - y, dz = qz - z;
            float aa = dx * dx, bb = dy * dy, cc = dz * dz;
            d2 = (aa + bb) + cc;
        }
        msk[s] = __ballot(d2 < r2);        // strict <, matches reference
        lbase[s] = run;
        run += __popcll(msk[s]);
    }
    if (lane == 0) s_wtot[wave] = run;
    __syncthreads();
    int w0 = s_wtot[0], w1 = s_wtot[1], w2 = s_wtot[2], w3 = s_wtot[3];
    int Bw = (wave > 0 ? w0 : 0) + (wave > 1 ? w1 : 0) + (wave > 2 ? w2 : 0);
    int cnt  = w0 + w1 + w2 + w3;
    int cntB = cnt < ns ? cnt : ns;        // real points kept
    const int npad = ns - cntB;

    // ---- Phase A pass 2: ordered compaction into LDS, w = |p|^2 ----
    #pragma unroll 4
    for (int s = 0; s < 16; ++s) {
        int gb = Bw + lbase[s];            // wave-uniform
        if (gb >= ns) break;
        unsigned long long mk = msk[s];
        bool in = (mk >> lane) & 1ull;
        int pos = gb + __popcll(mk & ((1ull << lane) - 1ull));
        if (in && pos < ns) {
            int n = wave * 1024 + s * 64 + lane;
            float x = base[3 * n], y = base[3 * n + 1], z = base[3 * n + 2];
            float sq = fmaf(x, x, fmaf(y, y, z * z));
            gpts[pos] = make_float4(x, y, z, sq);
        }
    }
    if (t < 8) gpts[cntB + t] = make_float4(1e6f, 1e6f, 1e6f, 3e12f);  // sentinels (huge h)
    __syncthreads();

    // ---- Phase B: 2nd-smallest h (incl. self) via med3; d2 = sq_i + m2 ----
    float sum = 0.0f;
    if (cntB > 256) {
        // 256 < cntB <= 409: thread owns i0=t and (maybe) i1=t+256; shared j reads.
        const int i0 = t, i1 = t + 256;
        const bool a1 = i1 < cntB;
        float4 p0 = gpts[i0];
        float4 p1 = gpts[a1 ? i1 : 0];
        float m10 = 1e30f, m20 = 1e30f;
        float m11 = 1e30f, m21 = 1e30f;
        for (int jt = 0; jt < cntB; jt += 8) {
            #pragma unroll
            for (int u = 0; u < 8; ++u) {
                float4 a = gpts[jt + u];
                float tt, h;
                tt = p0.x * a.x; tt = fmaf(p0.y, a.y, tt); tt = fmaf(p0.z, a.z, tt);
                h = fmaf(-2.0f, tt, a.w);
                m20 = __builtin_amdgcn_fmed3f(m10, m20, h);
                m10 = fminf(m10, h);
                tt = p1.x * a.x; tt = fmaf(p1.y, a.y, tt); tt = fmaf(p1.z, a.z, tt);
                h = fmaf(-2.0f, tt, a.w);
                m21 = __builtin_amdgcn_fmed3f(m11, m21, h);
                m11 = fminf(m11, h);
            }
        }
        float d0 = fmaxf(p0.w + m20, 0.0f);
        float d1 = fmaxf(p1.w + m21, 0.0f);
        if (!(i0 == 0 && npad > 0)) sum += sqrtf(d0);
        if (a1) sum += sqrtf(d1);
    } else {
        for (int i = t; i < cntB; i += 256) {
            float4 pi = gpts[i];
            float m1 = 1e30f, m2 = 1e30f;
            for (int jt = 0; jt < cntB; jt += 8) {
                #pragma unroll
                for (int u = 0; u < 8; ++u) {
                    float4 a = gpts[jt + u];
                    float tt, h;
                    tt = pi.x * a.x; tt = fmaf(pi.y, a.y, tt); tt = fmaf(pi.z, a.z, tt);
                    h = fmaf(-2.0f, tt, a.w);
                    m2 = __builtin_amdgcn_fmed3f(m1, m2, h);
                    m1 = fminf(m1, h);
                }
            }
            float dmin = fmaxf(pi.w + m2, 0.0f);
            if (!(i == 0 && npad > 0)) sum += sqrtf(dmin);
        }
    }
    #pragma unroll
    for (int off = 32; off; off >>= 1) sum += __shfl_down(sum, off);
    if (lane == 0) s_part[wave] = sum;
    __syncthreads();
    if (t == 0) {
        float tot = s_part[0] + s_part[1] + s_part[2] + s_part[3] + 0.1f * (float)ns;
        float u  = tot / (float)ns;
        float du = u - P.expect_len;
        partials[xid] = du * du / (P.expect_len + 0.1f) * P.wscale[pidx];
    }
}

// ---------------------------------------------------------------------------
// Kernel 3: sum the 2040 per-block partials -> d_out (no atomics anywhere).
// ---------------------------------------------------------------------------
__global__ __launch_bounds__(256) void reduce_kernel(const float* __restrict__ partials,
                                                     float* __restrict__ out) {
    const int t = threadIdx.x;
    __shared__ float sp[4];
    float s = 0.0f;
    for (int i = t; i < NPART; i += 256) s += partials[i];
    #pragma unroll
    for (int off = 32; off; off >>= 1) s += __shfl_down(s, off);
    if ((t & 63) == 0) sp[t >> 6] = s;
    __syncthreads();
    if (t == 0) out[0] = sp[0] + sp[1] + sp[2] + sp[3];
}

extern "C" void kernel_launch(void* const* d_in, const int* in_sizes, int n_in,
                              void* d_out, int out_size, void* d_ws, size_t ws_size,
                              hipStream_t stream) {
    const float* pcd = (const float*)d_in[0];
    const int B = in_sizes[0] / (NPTS * 3);   // = 2
    float* out = (float*)d_out;
    int*   fps = (int*)d_ws;                  // [0, NGROUP) ints
    float* partials = (float*)d_ws + NGROUP;  // [NGROUP, NGROUP+NPART) floats

    fps_kernel<<<dim3(B), dim3(FPS_T), 0, stream>>>(pcd, fps);

    LossParams P;
    const double ps[NPCT] = {0.02, 0.04, 0.06, 0.08, 0.10};
    for (int i = 0; i < NPCT; ++i) {
        P.nsample[i] = (int)(NPTS * ps[i]);
        double r = std::sqrt(ps[i] * 1.0);
        P.r2[i] = (float)(r * r);
        double w = (ps[i] * 100.0) * (ps[i] * 100.0);
        P.wscale[i] = (float)(w / (double)(B * NPOINT * NPCT));
    }
    P.expect_len = (float)std::sqrt(3.14159265358979323846 / (double)NPTS);

    group_kernel<<<dim3(NPART), dim3(256), 0, stream>>>(pcd, fps, partials, P);
    reduce_kernel<<<dim3(1), dim3(256), 0, stream>>>(partials, out);
}

// Round 6
// 214.626 us; speedup vs baseline: 1.2854x; 1.0051x over previous
//
#include <hip/hip_runtime.h>
#include <cmath>

#define NPTS 4096
#define NPOINT 204   // int(4096 * 0.05)
#define NPCT 5
#define MAXNS 409    // int(4096 * 0.10)
#define FPS_T 256
#define NGROUP 408   // B * NPOINT
#define NPART (NGROUP * NPCT)
#define MAXSLOT 7    // ceil(409/64)

typedef unsigned long long u64;
typedef float f32x2 __attribute__((ext_vector_type(2)));

struct LossParams {
    int   nsample[NPCT];
    float r2[NPCT];
    float wscale[NPCT];   // (p*100)^2 / (B*NPOINT*NPCT)
    float expect_len;
};

// ---------------- DPP wave64 reductions ------------------------------------
template <int CTRL>
__device__ __forceinline__ int dpp_imax(int v) {
    int t = __builtin_amdgcn_update_dpp(0, v, CTRL, 0xf, 0xf, true);
    return v > t ? v : t;
}
template <int CTRL>
__device__ __forceinline__ int dpp_imin(int v) {
    int t = __builtin_amdgcn_update_dpp(0x7fffffff, v, CTRL, 0xf, 0xf, false);
    return v < t ? v : t;
}
__device__ __forceinline__ int wave_max_i(int v) {
    v = dpp_imax<0x111>(v); v = dpp_imax<0x112>(v);
    v = dpp_imax<0x114>(v); v = dpp_imax<0x118>(v);
    v = dpp_imax<0x142>(v); v = dpp_imax<0x143>(v);
    return __builtin_amdgcn_readlane(v, 63);
}
__device__ __forceinline__ int wave_min_i(int v) {
    v = dpp_imin<0x111>(v); v = dpp_imin<0x112>(v);
    v = dpp_imin<0x114>(v); v = dpp_imin<0x118>(v);
    v = dpp_imin<0x142>(v); v = dpp_imin<0x143>(v);
    return __builtin_amdgcn_readlane(v, 63);
}
template <int CTRL>
__device__ __forceinline__ u64 dpp_u64max(u64 v) {
    int lo = (int)(unsigned)v;
    int hi = (int)(unsigned)(v >> 32);
    unsigned slo = (unsigned)__builtin_amdgcn_update_dpp(0, lo, CTRL, 0xf, 0xf, true);
    unsigned shi = (unsigned)__builtin_amdgcn_update_dpp(0, hi, CTRL, 0xf, 0xf, true);
    u64 o = ((u64)shi << 32) | slo;
    return v > o ? v : o;
}

// ---------------------------------------------------------------------------
// Kernel 1: FPS — UNCHANGED from R5 (proven 118.5 µs, exact tie semantics).
// ---------------------------------------------------------------------------
__global__ __launch_bounds__(FPS_T) void fps_kernel(const float* __restrict__ pcd,
                                                    int* __restrict__ fps_idx) {
#pragma clang fp contract(off)
    __shared__ float4 pts[NPTS];        // 64 KB
    __shared__ u64 keys[2][4];          // ping-pong: 1 barrier/iter

    const int b = blockIdx.x;
    const int t = threadIdx.x;
    const int wave = t >> 6, lane = t & 63;
    const float* base = pcd + (size_t)b * NPTS * 3;

    f32x2 X[8], Y[8], Z[8], D[8];
    #pragma unroll
    for (int q = 0; q < 8; ++q) {
        int n0 = (2 * q) * FPS_T + t;
        int n1 = (2 * q + 1) * FPS_T + t;
        float x0 = base[3 * n0 + 0], y0 = base[3 * n0 + 1], z0 = base[3 * n0 + 2];
        float x1 = base[3 * n1 + 0], y1 = base[3 * n1 + 1], z1 = base[3 * n1 + 2];
        pts[n0] = make_float4(x0, y0, z0, 0.0f);
        pts[n1] = make_float4(x1, y1, z1, 0.0f);
        X[q] = (f32x2){x0, x1};
        Y[q] = (f32x2){y0, y1};
        Z[q] = (f32x2){z0, z1};
        D[q] = (f32x2){1e10f, 1e10f};
    }
    int* out = fps_idx + b * NPOINT;
    if (t == 0) out[0] = 0;
    __syncthreads();

    float4 c = pts[0];
    for (int it = 1; it < NPOINT; ++it) {
        f32x2 cxx = (f32x2){c.x, c.x};
        f32x2 cyy = (f32x2){c.y, c.y};
        f32x2 czz = (f32x2){c.z, c.z};
        int bb = -1, bi = 0;
        #pragma unroll
        for (int q = 0; q < 8; ++q) {
            f32x2 dx = X[q] - cxx, dy = Y[q] - cyy, dz = Z[q] - czz;
            f32x2 d  = (dx * dx + dy * dy) + dz * dz;
            f32x2 dd = D[q];
            float d0 = fminf(dd.x, d.x);
            float d1 = fminf(dd.y, d.y);
            D[q] = (f32x2){d0, d1};
            int b0 = __float_as_int(d0);
            int b1 = __float_as_int(d1);
            if (b0 > bb) { bb = b0; bi = (2 * q) * FPS_T + t; }
            if (b1 > bb) { bb = b1; bi = (2 * q + 1) * FPS_T + t; }
        }
        int wmax = wave_max_i(bb);
        int cand = (bb == wmax) ? bi : 0x7fffffff;
        int widx = wave_min_i(cand);
        if (lane == 0)
            keys[it & 1][wave] =
                ((u64)(unsigned)wmax << 32) | (unsigned)~(unsigned)widx;
        __syncthreads();
        u64 kv = keys[it & 1][lane & 3];
        kv = dpp_u64max<0x111>(kv);
        kv = dpp_u64max<0x112>(kv);
        unsigned lo3 = (unsigned)__builtin_amdgcn_readlane((int)(unsigned)kv, 3);
        int last = (int)~lo3;
        c = pts[last];
        if (t == 0) out[it] = last;
    }
}

// ---- Phase B worker: K i-slots/lane, j streamed over this wave's quarter ---
// min2 (smallest two incl. self) tracking via med3; exact reference k=2 KNN.
template <int K>
__device__ __forceinline__ void phaseB(const float4* __restrict__ gpts,
                                       float2 (*wres)[64],   // [MAXSLOT][64], this wave's slab
                                       int j0, int j1, int lane, int cntB) {
    float4 pi[K];
    float m1[K], m2[K];
    #pragma unroll
    for (int s = 0; s < K; ++s) {
        int idx = s * 64 + lane;
        pi[s] = gpts[idx < cntB ? idx : 0];   // dummy lanes skipped at merge
        m1[s] = 1e30f; m2[s] = 1e30f;
    }
    #pragma unroll 2
    for (int j = j0; j < j1; ++j) {
        float4 a = gpts[j];                   // wave-uniform broadcast read
        #pragma unroll
        for (int s = 0; s < K; ++s) {
            float tt = pi[s].x * a.x;
            tt = fmaf(pi[s].y, a.y, tt);
            tt = fmaf(pi[s].z, a.z, tt);
            float h = fmaf(-2.0f, tt, a.w);   // |a|^2 - 2<pi,a>
            m2[s] = __builtin_amdgcn_fmed3f(m1[s], m2[s], h);
            m1[s] = fminf(m1[s], h);
        }
    }
    #pragma unroll
    for (int s = 0; s < K; ++s) wres[s][lane] = (float2){m1[s], m2[s]};
}

// ---------------------------------------------------------------------------
// Kernel 2: one block per (group, percentage); pidx = blk % 5 (interleaved).
// Phase A: 2-barrier ballot compaction (order-preserving), w = |p|^2.
// Phase B: register-tiled i (all i's per lane), each wave streams ONLY its
// quarter of j -> 4x fewer broadcast LDS reads; exact min2-merge across waves.
// ---------------------------------------------------------------------------
__global__ __launch_bounds__(256) void group_kernel(const float* __restrict__ pcd,
                                                    const int* __restrict__ fps_idx,
                                                    float* __restrict__ partials,
                                                    LossParams P) {
    const int xid  = blockIdx.x;           // 0 .. NPART-1
    const int pidx = xid % NPCT;
    const int g    = xid / NPCT;           // 0 .. NGROUP-1
    const int b    = g / NPOINT;
    const int m    = g - b * NPOINT;
    const int t    = threadIdx.x;
    const int wave = t >> 6, lane = t & 63;

    const int   ns = P.nsample[pidx];
    const float r2 = P.r2[pidx];

    __shared__ float4 gpts[MAXNS];
    __shared__ float2 wres[4][MAXSLOT][64];  // 14.3 KB
    __shared__ int    s_wtot[4];
    __shared__ float  s_part[4];

    const float* base = pcd + (size_t)b * NPTS * 3;
    int qi = fps_idx[b * NPOINT + m];
    float qx = base[3 * qi + 0], qy = base[3 * qi + 1], qz = base[3 * qi + 2];

    // ---- Phase A pass 1: ballot the wave's 16 sub-chunks of 64 points ----
    unsigned long long msk[16];
    int lbase[16];
    int run = 0;
    #pragma unroll 4
    for (int s = 0; s < 16; ++s) {
        int n = wave * 1024 + s * 64 + lane;
        float x = base[3 * n + 0];
        float y = base[3 * n + 1];
        float z = base[3 * n + 2];
        float d2;
        {
#pragma clang fp contract(off)
            float dx = qx - x, dy = qy - y, dz = qz - z;
            float aa = dx * dx, bb = dy * dy, cc = dz * dz;
            d2 = (aa + bb) + cc;
        }
        msk[s] = __ballot(d2 < r2);        // strict <, matches reference
        lbase[s] = run;
        run += __popcll(msk[s]);
    }
    if (lane == 0) s_wtot[wave] = run;
    __syncthreads();
    int w0 = s_wtot[0], w1 = s_wtot[1], w2 = s_wtot[2], w3 = s_wtot[3];
    int Bw = (wave > 0 ? w0 : 0) + (wave > 1 ? w1 : 0) + (wave > 2 ? w2 : 0);
    int cnt  = w0 + w1 + w2 + w3;
    int cntB = cnt < ns ? cnt : ns;        // real points kept
    const int npad = ns - cntB;

    // ---- Phase A pass 2: ordered compaction into LDS, w = |p|^2 ----
    #pragma unroll 4
    for (int s = 0; s < 16; ++s) {
        int gb = Bw + lbase[s];            // wave-uniform
        if (gb >= ns) break;
        unsigned long long mk = msk[s];
        bool in = (mk >> lane) & 1ull;
        int pos = gb + __popcll(mk & ((1ull << lane) - 1ull));
        if (in && pos < ns) {
            int n = wave * 1024 + s * 64 + lane;
            float x = base[3 * n], y = base[3 * n + 1], z = base[3 * n + 2];
            float sq = fmaf(x, x, fmaf(y, y, z * z));
            gpts[pos] = make_float4(x, y, z, sq);
        }
    }
    __syncthreads();

    // ---- Phase B: each wave streams its quarter of j ----
    const int quarter = (cntB + 3) >> 2;
    const int j0 = wave * quarter;
    const int j1 = (j0 + quarter) < cntB ? (j0 + quarter) : cntB;
    const int nslot = (cntB + 63) >> 6;    // 1..7
    switch (nslot) {
        case 1: phaseB<1>(gpts, wres[wave], j0, j1, lane, cntB); break;
        case 2: phaseB<2>(gpts, wres[wave], j0, j1, lane, cntB); break;
        case 3: phaseB<3>(gpts, wres[wave], j0, j1, lane, cntB); break;
        case 4: phaseB<4>(gpts, wres[wave], j0, j1, lane, cntB); break;
        case 5: phaseB<5>(gpts, wres[wave], j0, j1, lane, cntB); break;
        case 6: phaseB<6>(gpts, wres[wave], j0, j1, lane, cntB); break;
        default: phaseB<7>(gpts, wres[wave], j0, j1, lane, cntB); break;
    }
    __syncthreads();

    // ---- Merge 4 waves' min2 pairs per i; then sum sqrt ----
    float sum = 0.0f;
    for (int it = t; it < nslot * 64; it += 256) {
        int i = it;                        // = s*64 + l
        if (i < cntB) {
            int s = it >> 6, l = it & 63;
            float2 a = wres[0][s][l];
            float2 bq = wres[1][s][l];
            float2 cq = wres[2][s][l];
            float2 dq = wres[3][s][l];
            // exact min2 merge: m1=min(a1,b1); m2=min(max(a1,b1),min(a2,b2))
            float e1 = fminf(a.x, bq.x), e2 = fminf(fmaxf(a.x, bq.x), fminf(a.y, bq.y));
            float f1 = fminf(cq.x, dq.x), f2 = fminf(fmaxf(cq.x, dq.x), fminf(cq.y, dq.y));
            float m2v = fminf(fmaxf(e1, f1), fminf(e2, f2));
            float sq = gpts[i].w;
            float d2 = fmaxf(sq + m2v, 0.0f);
            // pads duplicate gpts[0] => i=0's nn is exactly 0 when npad>0
            if (!(i == 0 && npad > 0)) sum += sqrtf(d2);
        }
    }
    #pragma unroll
    for (int off = 32; off; off >>= 1) sum += __shfl_down(sum, off);
    if (lane == 0) s_part[wave] = sum;
    __syncthreads();
    if (t == 0) {
        float tot = s_part[0] + s_part[1] + s_part[2] + s_part[3] + 0.1f * (float)ns;
        float u  = tot / (float)ns;
        float du = u - P.expect_len;
        partials[xid] = du * du / (P.expect_len + 0.1f) * P.wscale[pidx];
    }
}

// ---------------------------------------------------------------------------
// Kernel 3: sum the 2040 per-block partials -> d_out (no atomics anywhere).
// ---------------------------------------------------------------------------
__global__ __launch_bounds__(256) void reduce_kernel(const float* __restrict__ partials,
                                                     float* __restrict__ out) {
    const int t = threadIdx.x;
    __shared__ float sp[4];
    float s = 0.0f;
    for (int i = t; i < NPART; i += 256) s += partials[i];
    #pragma unroll
    for (int off = 32; off; off >>= 1) s += __shfl_down(s, off);
    if ((t & 63) == 0) sp[t >> 6] = s;
    __syncthreads();
    if (t == 0) out[0] = sp[0] + sp[1] + sp[2] + sp[3];
}

extern "C" void kernel_launch(void* const* d_in, const int* in_sizes, int n_in,
                              void* d_out, int out_size, void* d_ws, size_t ws_size,
                              hipStream_t stream) {
    const float* pcd = (const float*)d_in[0];
    const int B = in_sizes[0] / (NPTS * 3);   // = 2
    float* out = (float*)d_out;
    int*   fps = (int*)d_ws;                  // [0, NGROUP) ints
    float* partials = (float*)d_ws + NGROUP;  // [NGROUP, NGROUP+NPART) floats

    fps_kernel<<<dim3(B), dim3(FPS_T), 0, stream>>>(pcd, fps);

    LossParams P;
    const double ps[NPCT] = {0.02, 0.04, 0.06, 0.08, 0.10};
    for (int i = 0; i < NPCT; ++i) {
        P.nsample[i] = (int)(NPTS * ps[i]);
        double r = std::sqrt(ps[i] * 1.0);
        P.r2[i] = (float)(r * r);
        double w = (ps[i] * 100.0) * (ps[i] * 100.0);
        P.wscale[i] = (float)(w / (double)(B * NPOINT * NPCT));
    }
    P.expect_len = (float)std::sqrt(3.14159265358979323846 / (double)NPTS);

    group_kernel<<<dim3(NPART), dim3(256), 0, stream>>>(pcd, fps, partials, P);
    reduce_kernel<<<dim3(1), dim3(256), 0, stream>>>(partials, out);
}